// Round 12
// baseline (1218.699 us; speedup 1.0000x reference)
//
#include <hip/hip_runtime.h>
#include <math.h>

namespace {

constexpr int TSEQ   = 2048;
constexpr int DIN    = 16;
constexpr int NH1    = 5;
constexpr int NH2    = 50;
constexpr int NCLS   = 20;
constexpr int CHUNK  = 64;
constexpr int NCHUNK = TSEQ / CHUNK;
constexpr int BATCH  = 256;
constexpr int GXS    = 21;   // gx row stride (odd -> conflict-free)

typedef _Float16 v2h __attribute__((ext_vector_type(2)));
typedef _Float16 v8h __attribute__((ext_vector_type(8)));

#if __has_builtin(__builtin_amdgcn_fdot2)
#define FDOT2(a, b, c) __builtin_amdgcn_fdot2((a), (b), (c), false)
#else
#define FDOT2(a, b, c) fmaf((float)(a)[0], (float)(b)[0], \
                        fmaf((float)(a)[1], (float)(b)[1], (c)))
#endif

// No clamp: exp(+inf)->inf, rcp(inf)->0 — still correct; inputs bounded.
__device__ __forceinline__ float fast_sigm(float x) {
    return __fdividef(1.f, 1.f + __expf(-x));
}
// tanh(x) = 2*sigm(2x) - 1
__device__ __forceinline__ float fast_tanh(float x) {
    return fmaf(2.f, fast_sigm(2.f * x), -1.f);
}

// quad_perm DPP: VALU-speed cross-lane within aligned quads.
template <int CTRL>
__device__ __forceinline__ float qperm(float v) {
    int i = __builtin_bit_cast(int, v);
    int r = __builtin_amdgcn_update_dpp(i, i, CTRL, 0xf, 0xf, false);
    return __builtin_bit_cast(float, r);
}
__device__ __forceinline__ float rdlane(float v, int lane) {
    return __builtin_bit_cast(float,
        __builtin_amdgcn_readlane(__builtin_bit_cast(int, v), lane));
}

struct L1State {
    float c1;
    float h0, h1, h2, h3, h4;   // wave-uniform -> SGPRs
};

// One L1 timestep. Lane 4j+g owns row r=g*5+j (j<5); fp32 throughout.
__device__ __forceinline__ void l1_step(float gx, float bias1,
                                        const float* __restrict__ w1h,
                                        float isc1, float osc1, float off1,
                                        L1State& st) {
    float g1 = gx + bias1;
    g1 = fmaf(st.h0, w1h[0], g1);
    g1 = fmaf(st.h1, w1h[1], g1);
    g1 = fmaf(st.h2, w1h[2], g1);
    g1 = fmaf(st.h3, w1h[3], g1);
    g1 = fmaf(st.h4, w1h[4], g1);
    float act = fmaf(osc1, fast_sigm(isc1 * g1), off1);
    float f_ = qperm<0xB1>(act);
    float gg = qperm<0x4E>(act);
    float o_ = qperm<0x1B>(act);
    st.c1 = fmaf(f_, st.c1, act * gg);          // valid on lanes 4j+0
    float h1me = o_ * fast_tanh(st.c1);
    st.h0 = rdlane(h1me, 0);
    st.h1 = rdlane(h1me, 4);
    st.h2 = rdlane(h1me, 8);
    st.h3 = rdlane(h1me, 12);
    st.h4 = rdlane(h1me, 16);
}

// ONE WAVE per batch element, ZERO barriers. Lane u (<50) owns all 4 gates
// of L2 unit u. Weights in fp16 pairs (100 VGPRs) -> fits the 256 arch-VGPR
// budget that killed R10. Matvec = 100 v_dot2_f32_f16 (fp32 accum). h2
// crosses lanes as fp16 through LDS: 1 ds_write_b16 + 7 ds_read_b128,
// single buffer (lockstep wave: all reads precede the write).
__global__ __launch_bounds__(64, 1) void lstm_fused_kernel(
    const float* __restrict__ x,     // (256,2048,16)
    const float* __restrict__ W1ih,  // (20,16)
    const float* __restrict__ W1hh,  // (20,5)
    const float* __restrict__ b1ih,  // (20)
    const float* __restrict__ b1hh,  // (20)
    const float* __restrict__ W2ih,  // (200,5)
    const float* __restrict__ W2hh,  // (200,50)
    const float* __restrict__ b2ih,  // (200)
    const float* __restrict__ b2hh,  // (200)
    const float* __restrict__ Wfc,   // (20,50)
    const float* __restrict__ bfc,   // (20)
    float* __restrict__ out)         // result(256,20) ++ last(256,50)
{
    const int b    = blockIdx.x;
    const int lane = threadIdx.x;    // single wave

    __shared__ float s_w1[NCLS * DIN];                 // 320
    __shared__ float s_gx[(CHUNK + 1) * GXS];          // x-part gates (+pad)
    __shared__ __align__(16) _Float16 s_h2h[64];       // h2 state, fp16

    for (int i = lane; i < NCLS * DIN; i += 64) s_w1[i] = W1ih[i];
    s_h2h[lane] = (_Float16)0.f;

    // ---- layer-1: lane 4j+g owns row r = g*5+j (lanes 0..19) ----
    const int r1 = (lane < NCLS) ? ((lane & 3) * NH1 + (lane >> 2)) : 0;
    float w1h[NH1];
    #pragma unroll
    for (int j = 0; j < NH1; ++j) w1h[j] = W1hh[r1 * NH1 + j];
    const float bias1 = b1ih[r1] + b1hh[r1];
    const bool  isg1  = ((lane & 3) == 2) && (lane < NCLS);
    const float isc1  = isg1 ? 2.f : 1.f;
    const float osc1  = isg1 ? 2.f : 1.f;
    const float off1  = isg1 ? -1.f : 0.f;

    // ---- layer-2: lane u owns unit u, all 4 gates, full K=50, fp16 ----
    const int u    = (lane < NH2) ? lane : 0;
    const bool on2 = (lane < NH2);

    v2h wg[4][25];       // W2hh rows as fp16 pairs: 100 VGPRs
    float w2i[4][NH1];   // W2ih fp32 (20 regs)
    float b2[4];
    #pragma unroll
    for (int gi = 0; gi < 4; ++gi) {
        const int rr = gi * NH2 + u;
        const float2* wr = (const float2*)(W2hh + rr * NH2);
        #pragma unroll
        for (int j = 0; j < 25; ++j) {
            float2 v = wr[j];
            wg[gi][j] = v2h{(_Float16)v.x, (_Float16)v.y};
        }
        #pragma unroll
        for (int d = 0; d < NH1; ++d) w2i[gi][d] = W2ih[rr * NH1 + d];
        b2[gi] = b2ih[rr] + b2hh[rr];
    }

    L1State st = {0.f, 0.f, 0.f, 0.f, 0.f, 0.f};
    float c2 = 0.f, hlast = 0.f;

    // x: lane = step-in-chunk; 16 floats = 4 float4, prefetched per chunk
    const float* xb = x + (size_t)b * TSEQ * DIN;
    float4 xr[4];
    #pragma unroll
    for (int i = 0; i < 4; ++i)
        xr[i] = ((const float4*)(xb + (size_t)lane * DIN))[i];

    // ---- one timestep; zero barriers (lockstep single wave) ----
    #define LSTM_STEP(TT, DO_L1)                                               \
    {                                                                          \
        v8h hr[7];                                                             \
        {                                                                      \
            const v8h* hb = (const v8h*)s_h2h;   /* broadcast b128 reads */    \
            _Pragma("unroll")                                                  \
            for (int j = 0; j < 7; ++j) hr[j] = hb[j];                         \
        }                                                                      \
        float gxn = s_gx[(TT + 1) * GXS + r1];                                 \
        /* ih part + bias with h1(t) (issues while LDS reads in flight) */     \
        float a0 = b2[0], a1 = b2[1], a2 = b2[2], a3 = b2[3];                  \
        _Pragma("unroll")                                                      \
        for (int d = 0; d < NH1; ++d) {                                        \
            const float hv = (d == 0) ? st.h0 : (d == 1) ? st.h1               \
                             : (d == 2) ? st.h2 : (d == 3) ? st.h3 : st.h4;    \
            a0 = fmaf(hv, w2i[0][d], a0);                                      \
            a1 = fmaf(hv, w2i[1][d], a1);                                      \
            a2 = fmaf(hv, w2i[2][d], a2);                                      \
            a3 = fmaf(hv, w2i[3][d], a3);                                      \
        }                                                                      \
        /* hh matvec: 100 v_dot2_f32_f16, 4 independent chains */              \
        _Pragma("unroll")                                                      \
        for (int r = 0; r < 7; ++r) {                                          \
            _Pragma("unroll")                                                  \
            for (int p = 0; p < 4; ++p) {                                      \
                const int j = r * 4 + p;                                       \
                if (j < 25) {                                                  \
                    v2h hh = {hr[r][2 * p], hr[r][2 * p + 1]};                 \
                    a0 = FDOT2(hh, wg[0][j], a0);                              \
                    a1 = FDOT2(hh, wg[1][j], a1);                              \
                    a2 = FDOT2(hh, wg[2][j], a2);                              \
                    a3 = FDOT2(hh, wg[3][j], a3);                              \
                }                                                              \
            }                                                                  \
        }                                                                      \
        /* L1 for step t+1 (independent; overlaps gate-act latency) */         \
        if (DO_L1)                                                             \
            l1_step(gxn, bias1, w1h, isc1, osc1, off1, st);                    \
        float i2  = fast_sigm(a0);                                             \
        float f2  = fast_sigm(a1);                                             \
        float gg2 = fast_tanh(a2);                                             \
        float o2  = fast_sigm(a3);                                             \
        c2 = fmaf(f2, c2, i2 * gg2);                                           \
        hlast = o2 * fast_tanh(c2);                                            \
        if (on2) s_h2h[lane] = (_Float16)hlast;   /* 1 ds_write_b16 */         \
        __builtin_amdgcn_wave_barrier();                                       \
    }

    #pragma unroll 1
    for (int c = 0; c < NCHUNK; ++c) {
        // ---- gx phase: lane = step; 20 rows x 16-dot from broadcast W1 ----
        {
            const float* xf = (const float*)xr;
            #pragma unroll 4
            for (int rw = 0; rw < NCLS; ++rw) {
                const float4* wv4 = (const float4*)(s_w1 + rw * DIN);
                float4 w0 = wv4[0], w1 = wv4[1], w2_ = wv4[2], w3 = wv4[3];
                float s = w0.x * xf[0];
                s = fmaf(w0.y, xf[1], s);  s = fmaf(w0.z, xf[2], s);  s = fmaf(w0.w, xf[3], s);
                s = fmaf(w1.x, xf[4], s);  s = fmaf(w1.y, xf[5], s);  s = fmaf(w1.z, xf[6], s);
                s = fmaf(w1.w, xf[7], s);  s = fmaf(w2_.x, xf[8], s); s = fmaf(w2_.y, xf[9], s);
                s = fmaf(w2_.z, xf[10], s); s = fmaf(w2_.w, xf[11], s); s = fmaf(w3.x, xf[12], s);
                s = fmaf(w3.y, xf[13], s); s = fmaf(w3.z, xf[14], s); s = fmaf(w3.w, xf[15], s);
                s_gx[lane * GXS + rw] = s;   // stride 21 -> conflict-free
            }
        }
        // prefetch next chunk's x (stays in flight across the step loop)
        {
            const int cn = (c + 1 < NCHUNK) ? c + 1 : c;
            const float4* xs = (const float4*)(xb + ((size_t)cn * CHUNK + lane) * DIN);
            #pragma unroll
            for (int i = 0; i < 4; ++i) xr[i] = xs[i];
        }
        __builtin_amdgcn_wave_barrier();   // gx writes before step reads

        // chunk preamble: L1 for this chunk's step 0
        l1_step(s_gx[r1], bias1, w1h, isc1, osc1, off1, st);

        #pragma unroll 2
        for (int tt = 0; tt < CHUNK; ++tt) {
            LSTM_STEP(tt, (tt < CHUNK - 1))
        }
    }
    #undef LSTM_STEP

    // ---- outputs: result(256,20) @0, last(256,50) @5120 ----
    if (lane < NH2) out[BATCH * NCLS + b * NH2 + lane] = hlast;   // fp32 'last'
    // fc head: publish fp32 h2 via s_gx scratch (single wave, in-order)
    if (lane < NH2) s_gx[lane] = hlast;
    __builtin_amdgcn_wave_barrier();
    if (lane < NCLS) {
        float acc = bfc[lane];
        const float* wr = Wfc + lane * NH2;
        #pragma unroll
        for (int j = 0; j < NH2; ++j) acc = fmaf(s_gx[j], wr[j], acc);
        out[b * NCLS + lane] = acc;
    }
}

} // namespace

extern "C" void kernel_launch(void* const* d_in, const int* in_sizes, int n_in,
                              void* d_out, int out_size, void* d_ws, size_t ws_size,
                              hipStream_t stream) {
    (void)in_sizes; (void)n_in; (void)d_ws; (void)ws_size; (void)out_size;
    const float* x    = (const float*)d_in[0];
    const float* W1ih = (const float*)d_in[1];
    const float* W1hh = (const float*)d_in[2];
    const float* b1ih = (const float*)d_in[3];
    const float* b1hh = (const float*)d_in[4];
    const float* W2ih = (const float*)d_in[5];
    const float* W2hh = (const float*)d_in[6];
    const float* b2ih = (const float*)d_in[7];
    const float* b2hh = (const float*)d_in[8];
    const float* Wfc  = (const float*)d_in[9];
    const float* bfc  = (const float*)d_in[10];

    lstm_fused_kernel<<<dim3(BATCH), dim3(64), 0, stream>>>(
        x, W1ih, W1hh, b1ih, b1hh, W2ih, W2hh, b2ih, b2hh, Wfc, bfc,
        (float*)d_out);
}